// Round 1
// 533.924 us; speedup vs baseline: 1.0717x; 1.0717x over previous
//
#include <hip/hip_runtime.h>
#include <math.h>

// Problem constants
#define B_  4
#define L_  2048
#define D_  1024
#define H_  16
#define HD_ 64

typedef __attribute__((ext_vector_type(8))) short short8;
typedef __attribute__((ext_vector_type(4))) float f32x4;

// fp32 -> bf16 bits, round-to-nearest-even
__device__ static inline unsigned short f2bf(float f) {
    union { float f; unsigned int u; } v; v.f = f;
    const unsigned int u = v.u;
    return (unsigned short)((u + 0x7FFFu + ((u >> 16) & 1u)) >> 16);
}

// packed fp32x2 -> bf16x2 (single VALU op; T12 primitive)
__device__ static inline unsigned cvt_pk_bf16(float a, float b) {
    unsigned r;
    asm("v_cvt_pk_bf16_f32 %0, %1, %2" : "=v"(r) : "v"(a), "v"(b));
    return r;
}

__device__ static inline void async_copy16(const void* g, void* lds)
{
    __builtin_amdgcn_global_load_lds(
        (const __attribute__((address_space(1))) void*)g,
        (__attribute__((address_space(3))) void*)lds, 16, 0, 0);
}

// ---------------------------------------------------------------------------
// fp32 -> bf16 convert, 8 elements per thread
// ---------------------------------------------------------------------------
__global__ __launch_bounds__(256) void cvt_bf16_kernel(
    const float* __restrict__ in, unsigned short* __restrict__ out)
{
    const size_t i = ((size_t)blockIdx.x * 256 + threadIdx.x) * 8;
    const float4 x = *(const float4*)&in[i];
    const float4 y = *(const float4*)&in[i + 4];
    ushort4 o0, o1;
    o0.x = f2bf(x.x); o0.y = f2bf(x.y); o0.z = f2bf(x.z); o0.w = f2bf(x.w);
    o1.x = f2bf(y.x); o1.y = f2bf(y.y); o1.z = f2bf(y.z); o1.w = f2bf(y.w);
    *(ushort4*)&out[i]     = o0;
    *(ushort4*)&out[i + 4] = o1;
}

// ---------------------------------------------------------------------------
// Transpose + convert: WT[n][k] = bf16(W[k][n]), square N=1024
// ---------------------------------------------------------------------------
__global__ __launch_bounds__(256) void transpose_bf16_kernel(
    const float* __restrict__ W, unsigned short* __restrict__ WT)
{
    __shared__ float t[32][33];
    const int c  = threadIdx.x & 31;
    const int r8 = threadIdx.x >> 5;          // 0..7
    const int k0 = blockIdx.y * 32;
    const int n0 = blockIdx.x * 32;
    #pragma unroll
    for (int i = 0; i < 4; ++i) {
        const int r = r8 + i * 8;
        t[r][c] = W[(size_t)(k0 + r) * 1024 + n0 + c];
    }
    __syncthreads();
    #pragma unroll
    for (int i = 0; i < 4; ++i) {
        const int r = r8 + i * 8;
        WT[(size_t)(n0 + r) * 1024 + k0 + c] = f2bf(t[c][r]);
    }
}

// ---------------------------------------------------------------------------
// V transpose (bf16 in): Vb bf16 [B,L,D] -> vtb bf16 [B,H,HD,L]
// ---------------------------------------------------------------------------
__global__ __launch_bounds__(256) void vtrans_bf16_kernel(
    const unsigned short* __restrict__ Vb, unsigned short* __restrict__ vtb)
{
    __shared__ unsigned short t[64][68];     // 136B stride: 8B-aligned rows
    const int tid = threadIdx.x;
    const int l0  = blockIdx.x * 64;
    const int h   = blockIdx.y;
    const int b   = blockIdx.z;
    const int rr  = tid >> 4;          // 0..15
    const int c4  = (tid & 15) * 4;
    #pragma unroll
    for (int i = 0; i < 4; ++i) {
        const int r = i * 16 + rr;
        *(ushort4*)&t[r][c4] =
            *(const ushort4*)&Vb[((size_t)(b * L_ + l0 + r)) * D_ + h * 64 + c4];
    }
    __syncthreads();
    #pragma unroll
    for (int i = 0; i < 4; ++i) {
        const int d = i * 16 + rr;
        ushort4 o;
        o.x = t[c4 + 0][d]; o.y = t[c4 + 1][d];
        o.z = t[c4 + 2][d]; o.w = t[c4 + 3][d];
        *(ushort4*)&vtb[((size_t)((b * H_ + h) * 64 + d)) * L_ + l0 + c4] = o;
    }
}

// ---------------------------------------------------------------------------
// Pack mask -> per-(query, quad) 16-bit words:
// mbt[((b*32 + kt)*2048 + q)*4 + Q] bit (kr*4+r) = mask key kt*64+kr*16+Q*4+r
// Lane (quad Q, l15) in attn reads ONE ushort and bfe's its 4 nibbles.
// ---------------------------------------------------------------------------
__global__ __launch_bounds__(256) void pack_mask16_kernel(
    const int* __restrict__ mask, unsigned short* __restrict__ mbt)
{
    const unsigned g = blockIdx.x * 256 + threadIdx.x;
    const int v = mask[g];
    const unsigned long long bm = __ballot(v != 0);
    const int lane = threadIdx.x & 63;
    if (lane < 4) {
        const int b  = g >> 22;
        const int q  = (g >> 11) & 2047;
        const int kt = (g >> 6) & 31;
        unsigned long long x = (bm >> (4 * lane)) & 0x000F000F000F000FULL;
        x |= x >> 12;      // nibble kr=1 -> bits 4..7
        x |= x >> 24;      // kr=2 -> 8..11, kr=3 -> 12..15
        mbt[((size_t)(b * 32 + kt) * 2048 + q) * 4 + lane] =
            (unsigned short)(x & 0xFFFFu);
    }
}

// ---------------------------------------------------------------------------
// bf16 MFMA GEMM (m97 recipe): C = (A[M,K] @ WT[N,K]^T + bias) * omul
// OUT_BF16=1 -> C is bf16 (RNE); 0 -> fp32.
// ---------------------------------------------------------------------------
template<int OUT_BF16>
__global__ __launch_bounds__(256) void gemm_mfma_kernel(
    const unsigned short* __restrict__ A, const unsigned short* __restrict__ WT,
    const float* __restrict__ bias, void* __restrict__ Cv,
    int M, int N, int K, float omul)
{
    __shared__ __align__(16) unsigned short At[128 * 64];
    __shared__ __align__(16) unsigned short Bt[128 * 64];

    const int tid  = threadIdx.x;
    const int lane = tid & 63;
    const int wave = tid >> 6;
    const int wm   = wave >> 1;
    const int wn   = wave & 1;
    const int quad = lane >> 4;
    const int l15  = lane & 15;
    const int m0   = blockIdx.y * 128;
    const int n0   = blockIdx.x * 128;

    f32x4 acc[4][4];
    #pragma unroll
    for (int i = 0; i < 4; ++i)
        #pragma unroll
        for (int j = 0; j < 4; ++j) acc[i][j] = (f32x4)0.f;

    for (int k0 = 0; k0 < K; k0 += 64) {
        __syncthreads();
        #pragma unroll
        for (int i = 0; i < 4; ++i) {
            const int fb  = i * 256 + wave * 64;
            const int f   = fb + lane;
            const int row = f >> 3;
            const int c8  = f & 7;
            async_copy16(&A [(size_t)(m0 + row) * K + k0 + c8 * 8],
                         (char*)At + (size_t)fb * 16);
            async_copy16(&WT[(size_t)(n0 + row) * K + k0 + c8 * 8],
                         (char*)Bt + (size_t)fb * 16);
        }
        __syncthreads();

        #pragma unroll
        for (int kk = 0; kk < 64; kk += 32) {
            short8 afr[4], bfr[4];
            #pragma unroll
            for (int mt = 0; mt < 4; ++mt)
                afr[mt] = *(const short8*)&At[(size_t)(wm * 64 + mt * 16 + l15) * 64 + kk + quad * 8];
            #pragma unroll
            for (int nt = 0; nt < 4; ++nt)
                bfr[nt] = *(const short8*)&Bt[(size_t)(wn * 64 + nt * 16 + l15) * 64 + kk + quad * 8];
            #pragma unroll
            for (int mt = 0; mt < 4; ++mt)
                #pragma unroll
                for (int nt = 0; nt < 4; ++nt)
                    acc[mt][nt] = __builtin_amdgcn_mfma_f32_16x16x32_bf16(
                        afr[mt], bfr[nt], acc[mt][nt], 0, 0, 0);
        }
    }

    #pragma unroll
    for (int nt = 0; nt < 4; ++nt) {
        const int col = n0 + wn * 64 + nt * 16 + l15;
        const float bv = bias[col];
        #pragma unroll
        for (int mt = 0; mt < 4; ++mt) {
            const int r0 = m0 + wm * 64 + mt * 16 + quad * 4;
            #pragma unroll
            for (int r = 0; r < 4; ++r) {
                const float val = (acc[mt][nt][r] + bv) * omul;
                if constexpr (OUT_BF16)
                    ((unsigned short*)Cv)[(size_t)(r0 + r) * N + col] = f2bf(val);
                else
                    ((float*)Cv)[(size_t)(r0 + r) * N + col] = val;
            }
        }
    }
}

// ---------------------------------------------------------------------------
// MFMA flash attention, transposed orientation.
// Q pre-scaled by 0.125*log2e (folded into Q-GEMM epilogue).
// Kt/Vs LDS XOR-swizzled (T2, rule 21: linear dest + inv-swizzled global src
// + swizzled ds_read) -> conflict-free ds_read_b128.
// P -> bf16 via v_cvt_pk_bf16_f32 (T12 primitive).
// Defer-max rescale with THR=8 (T13).
// ---------------------------------------------------------------------------
#define AQ 128
#define AK 64
#define PSTR 72   // Pt row stride (bf16): 144B = 16B-aligned, low-conflict

__global__ __launch_bounds__(256) void attn_mfma_kernel(
    const unsigned short* __restrict__ Qb,
    const unsigned short* __restrict__ Kb,
    const unsigned short* __restrict__ Vtg,
    const unsigned short* __restrict__ mbt,
    unsigned short* __restrict__ Cb)
{
    __shared__ __align__(16) unsigned short Kt[AK * 64];        // [key][d] 8KB swz
    __shared__ __align__(16) unsigned short Vs[64 * AK];        // [d][key] 8KB swz
    __shared__ __align__(16) unsigned short Pt[AQ * PSTR];      // [q][key] 18KB
    __shared__ __align__(16) unsigned short Mt[AQ * 4];         // 1KB

    const int tid  = threadIdx.x;
    const int lane = tid & 63;
    const int w    = tid >> 6;          // wave 0..3: queries w*32..+31
    const int quad = lane >> 4;
    const int l15  = lane & 15;
    const int q0   = blockIdx.x * AQ;
    const int h    = blockIdx.y;
    const int b    = blockIdx.z;

    // Q fragments (B-operand): [qc][kc], resident in VGPRs (pre-scaled)
    short8 qf[2][2];
    #pragma unroll
    for (int qc = 0; qc < 2; ++qc)
        #pragma unroll
        for (int kc = 0; kc < 2; ++kc)
            qf[qc][kc] = *(const short8*)
                &Qb[((size_t)(b * L_ + q0 + w * 32 + qc * 16 + l15)) * D_
                    + h * 64 + kc * 32 + quad * 8];

    f32x4 ot[4][2];                     // ctx^T acc: [d-tile][q-tile]
    #pragma unroll
    for (int dr = 0; dr < 4; ++dr)
        #pragma unroll
        for (int qc = 0; qc < 2; ++qc) ot[dr][qc] = (f32x4)0.f;
    float m_run[2] = {-INFINITY, -INFINITY};
    float l_run[2] = {0.f, 0.f};

    for (int kt = 0; kt < L_ / AK; ++kt) {
        const int k0 = kt * AK;
        __syncthreads();   // previous tile's LDS reads complete
        // stage K tile [64 key][64 d] and V^T tile [64 d][64 key].
        // LDS dest linear; global source column chunk XOR'd with row&7 so a
        // swizzled ds_read retrieves logical data (both-sides involution).
        #pragma unroll
        for (int i = 0; i < 2; ++i) {
            const int fb = i * 256 + w * 64;
            const int f  = fb + lane;
            const int r  = f >> 3;
            const int cs = (f & 7) ^ (r & 7);
            async_copy16(&Kb[((size_t)(b * L_ + k0 + r)) * D_ + h * 64 + cs * 8],
                         (char*)Kt + fb * 16);
            async_copy16(&Vtg[((size_t)((b * H_ + h) * 64 + r)) * L_ + k0 + cs * 8],
                         (char*)Vs + fb * 16);
        }
        if (w == 3)   // mask tile: 128 q x 4 ushorts = 1KB contiguous
            async_copy16(&mbt[((size_t)(b * 32 + kt) * 2048 + q0) * 4 + lane * 8],
                         (char*)Mt);
        __syncthreads();   // drains vmcnt: tiles ready

        // ---- S^T = K·Q^T : st[key-tile][q-tile] -------------------------
        f32x4 st[4][2];
        {
            short8 kf[4];
            #pragma unroll
            for (int kr = 0; kr < 4; ++kr)
                kf[kr] = *(const short8*)
                    &Kt[(kr * 16 + l15) * 64 + ((quad ^ (l15 & 7)) * 8)];
            #pragma unroll
            for (int kr = 0; kr < 4; ++kr)
                #pragma unroll
                for (int qc = 0; qc < 2; ++qc)
                    st[kr][qc] = __builtin_amdgcn_mfma_f32_16x16x32_bf16(
                        kf[kr], qf[qc][0], (f32x4)0.f, 0, 0, 0);
        }
        {
            short8 kf[4];
            #pragma unroll
            for (int kr = 0; kr < 4; ++kr)
                kf[kr] = *(const short8*)
                    &Kt[(kr * 16 + l15) * 64 + (((4 + quad) ^ (l15 & 7)) * 8)];
            #pragma unroll
            for (int kr = 0; kr < 4; ++kr)
                #pragma unroll
                for (int qc = 0; qc < 2; ++qc)
                    st[kr][qc] = __builtin_amdgcn_mfma_f32_16x16x32_bf16(
                        kf[kr], qf[qc][1], st[kr][qc], 0, 0, 0);
        }

        // ---- online softmax (per-lane per query) + P write --------------
        #pragma unroll
        for (int qc = 0; qc < 2; ++qc) {
            const unsigned m16 = Mt[(w * 32 + qc * 16 + l15) * 4 + quad];
            float rmax = -INFINITY;
            #pragma unroll
            for (int kr = 0; kr < 4; ++kr) {
                const unsigned nib = (m16 >> (kr * 4)) & 0xFu;
                #pragma unroll
                for (int r = 0; r < 4; ++r) {
                    const float x = ((nib >> r) & 1u) ? st[kr][qc][r] : -INFINITY;
                    st[kr][qc][r] = x;
                    rmax = fmaxf(rmax, x);
                }
            }
            rmax = fmaxf(rmax, __shfl_xor(rmax, 16));
            rmax = fmaxf(rmax, __shfl_xor(rmax, 32));
            // T13 defer-max: skip rescale unless max grew by > 8 (exp2 dom)
            if (__any(rmax > m_run[qc] + 8.f)) {
                const float mnew  = fmaxf(m_run[qc], rmax);
                const float msafe = fmaxf(mnew, -1e30f);
                const float alpha = exp2f(m_run[qc] - msafe);
                l_run[qc] *= alpha;
                #pragma unroll
                for (int dr = 0; dr < 4; ++dr) {
                    ot[dr][qc][0] *= alpha; ot[dr][qc][1] *= alpha;
                    ot[dr][qc][2] *= alpha; ot[dr][qc][3] *= alpha;
                }
                m_run[qc] = mnew;
            }
            const float msafe = fmaxf(m_run[qc], -1e30f);
            float psum = 0.f;
            #pragma unroll
            for (int kr = 0; kr < 4; ++kr) {
                const float p0 = exp2f(st[kr][qc][0] - msafe);
                const float p1 = exp2f(st[kr][qc][1] - msafe);
                const float p2 = exp2f(st[kr][qc][2] - msafe);
                const float p3 = exp2f(st[kr][qc][3] - msafe);
                psum += (p0 + p1) + (p2 + p3);
                uint2 pk;
                pk.x = cvt_pk_bf16(p0, p1);
                pk.y = cvt_pk_bf16(p2, p3);
                *(uint2*)&Pt[(w * 32 + qc * 16 + l15) * PSTR + kr * 16 + quad * 4] = pk;
            }
            psum += __shfl_xor(psum, 16);
            psum += __shfl_xor(psum, 32);
            l_run[qc] += psum;
        }

        // ---- ctx^T += V^T · P^T  (Pt is wave-private; no barrier needed) -
        #pragma unroll
        for (int kc = 0; kc < 2; ++kc) {
            short8 vf[4], pf[2];
            #pragma unroll
            for (int dr = 0; dr < 4; ++dr)
                vf[dr] = *(const short8*)
                    &Vs[(dr * 16 + l15) * 64 + (((kc * 4 + quad) ^ (l15 & 7)) * 8)];
            #pragma unroll
            for (int qc = 0; qc < 2; ++qc)
                pf[qc] = *(const short8*)&Pt[(w * 32 + qc * 16 + l15) * PSTR
                                             + kc * 32 + quad * 8];
            #pragma unroll
            for (int dr = 0; dr < 4; ++dr)
                #pragma unroll
                for (int qc = 0; qc < 2; ++qc)
                    ot[dr][qc] = __builtin_amdgcn_mfma_f32_16x16x32_bf16(
                        vf[dr], pf[qc], ot[dr][qc], 0, 0, 0);
        }
    }

    // ---- epilogue: normalize, store ctx as bf16 [B,L,D] -----------------
    #pragma unroll
    for (int qc = 0; qc < 2; ++qc) {
        const float rinv = (l_run[qc] > 0.f) ? (1.f / l_run[qc]) : 0.f;
        const size_t base = ((size_t)(b * L_ + q0 + w * 32 + qc * 16 + l15)) * D_
                            + h * 64;
        #pragma unroll
        for (int dr = 0; dr < 4; ++dr) {
            ushort4 o;
            o.x = f2bf(ot[dr][qc][0] * rinv);
            o.y = f2bf(ot[dr][qc][1] * rinv);
            o.z = f2bf(ot[dr][qc][2] * rinv);
            o.w = f2bf(ot[dr][qc][3] * rinv);
            *(ushort4*)&Cb[base + dr * 16 + quad * 4] = o;
        }
    }
}

// ---------------------------------------------------------------------------
extern "C" void kernel_launch(void* const* d_in, const int* in_sizes, int n_in,
                              void* d_out, int out_size, void* d_ws, size_t ws_size,
                              hipStream_t stream)
{
    const float* q    = (const float*)d_in[0];
    const float* k    = (const float*)d_in[1];
    const float* v    = (const float*)d_in[2];
    const int*   mask = (const int*)d_in[3];
    const float* WQ   = (const float*)d_in[4];
    const float* bQ   = (const float*)d_in[5];
    const float* WK   = (const float*)d_in[6];
    const float* bK   = (const float*)d_in[7];
    const float* WV   = (const float*)d_in[8];
    const float* bV   = (const float*)d_in[9];
    const float* WO   = (const float*)d_in[10];
    const float* bO   = (const float*)d_in[11];
    float* out = (float*)d_out;

    const size_t NTOK = (size_t)B_ * L_;        // 8192

    // ws map (128 MiB): 8 x 16MB bf16 zones
    char* W = (char*)d_ws;
    unsigned short* qin = (unsigned short*)(W);                        // 16MB
    unsigned short* kin = (unsigned short*)(W + ((size_t)16  << 20));  // 16MB
    unsigned short* vin = (unsigned short*)(W + ((size_t)32  << 20));  // 16MB
    unsigned short* qbf = (unsigned short*)(W + ((size_t)48  << 20));  // 16MB
    unsigned short* kbf = (unsigned short*)(W + ((size_t)64  << 20));  // 16MB
    unsigned short* vbf = (unsigned short*)(W + ((size_t)80  << 20));  // 16MB
    unsigned short* vtb = (unsigned short*)(W + ((size_t)96  << 20));  // 16MB
    unsigned short* cb  = (unsigned short*)(W + ((size_t)112 << 20));  // 16MB
    // WTo reuses vin zone (dead after V GEMM); must live in ws, NOT d_out,
    // because the final GEMM writes out over all of d_out.
    unsigned short* WTo = vin;

    // d_out as scratch until final GEMM (all dead before the out-write):
    unsigned short* mbt16 = (unsigned short*)d_out;                          // 2MB
    unsigned short* WTq = (unsigned short*)((char*)d_out + ((size_t)2 << 20));
    unsigned short* WTk = (unsigned short*)((char*)d_out + ((size_t)4 << 20));
    unsigned short* WTv = (unsigned short*)((char*)d_out + ((size_t)6 << 20));

    pack_mask16_kernel<<<(B_ * L_ * L_) / 256, 256, 0, stream>>>(mask, mbt16);

    const int cvtg = (int)(NTOK * D_ / (256 * 8));   // 4096
    cvt_bf16_kernel<<<cvtg, 256, 0, stream>>>(q, qin);
    cvt_bf16_kernel<<<cvtg, 256, 0, stream>>>(k, kin);
    cvt_bf16_kernel<<<cvtg, 256, 0, stream>>>(v, vin);

    dim3 tg(32, 32);
    transpose_bf16_kernel<<<tg, 256, 0, stream>>>(WQ, WTq);
    transpose_bf16_kernel<<<tg, 256, 0, stream>>>(WK, WTk);
    transpose_bf16_kernel<<<tg, 256, 0, stream>>>(WV, WTv);

    // Projections, bf16 out. Q gets scale*log2e folded in (Q feeds only attn).
    const float qscale = 0.125f * 1.44269504088896340736f;
    dim3 ggrd(D_ / 128, NTOK / 128);            // (8, 64)
    gemm_mfma_kernel<1><<<ggrd, 256, 0, stream>>>(qin, WTq, bQ, qbf, (int)NTOK, D_, D_, qscale);
    gemm_mfma_kernel<1><<<ggrd, 256, 0, stream>>>(kin, WTk, bK, kbf, (int)NTOK, D_, D_, 1.f);
    gemm_mfma_kernel<1><<<ggrd, 256, 0, stream>>>(vin, WTv, bV, vbf, (int)NTOK, D_, D_, 1.f);

    // WO transpose into vin zone (dead now); V transpose to [B,H,HD,L]
    transpose_bf16_kernel<<<tg, 256, 0, stream>>>(WO, WTo);
    vtrans_bf16_kernel<<<dim3(L_ / 64, H_, B_), 256, 0, stream>>>(vbf, vtb);

    dim3 agrd(L_ / AQ, H_, B_);                 // (16, 16, 4)
    attn_mfma_kernel<<<agrd, 256, 0, stream>>>(qbf, kbf, vtb, mbt16, cb);

    gemm_mfma_kernel<0><<<ggrd, 256, 0, stream>>>(cb, WTo, bO, out, (int)NTOK, D_, D_, 1.f);
}

// Round 2
// 509.054 us; speedup vs baseline: 1.1240x; 1.0489x over previous
//
#include <hip/hip_runtime.h>
#include <math.h>

// Problem constants
#define B_  4
#define L_  2048
#define D_  1024
#define H_  16
#define HD_ 64

typedef __attribute__((ext_vector_type(8))) short short8;
typedef __attribute__((ext_vector_type(4))) float f32x4;

// fp32 -> bf16 bits, round-to-nearest-even
__device__ static inline unsigned short f2bf(float f) {
    union { float f; unsigned int u; } v; v.f = f;
    const unsigned int u = v.u;
    return (unsigned short)((u + 0x7FFFu + ((u >> 16) & 1u)) >> 16);
}

// packed fp32x2 -> bf16x2 (single VALU op; T12 primitive)
__device__ static inline unsigned cvt_pk_bf16(float a, float b) {
    unsigned r;
    asm("v_cvt_pk_bf16_f32 %0, %1, %2" : "=v"(r) : "v"(a), "v"(b));
    return r;
}

__device__ static inline void async_copy16(const void* g, void* lds)
{
    __builtin_amdgcn_global_load_lds(
        (const __attribute__((address_space(1))) void*)g,
        (__attribute__((address_space(3))) void*)lds, 16, 0, 0);
}

// ---------------------------------------------------------------------------
// fp32 -> bf16 convert, 8 elem/thread, 3 tensors in one launch (y selects)
// ---------------------------------------------------------------------------
__global__ __launch_bounds__(256) void cvt3_bf16_kernel(
    const float* __restrict__ i0, const float* __restrict__ i1,
    const float* __restrict__ i2,
    unsigned short* __restrict__ o0, unsigned short* __restrict__ o1,
    unsigned short* __restrict__ o2)
{
    const float* in = blockIdx.y == 0 ? i0 : blockIdx.y == 1 ? i1 : i2;
    unsigned short* out = blockIdx.y == 0 ? o0 : blockIdx.y == 1 ? o1 : o2;
    const size_t i = ((size_t)blockIdx.x * 256 + threadIdx.x) * 8;
    const float4 x = *(const float4*)&in[i];
    const float4 y = *(const float4*)&in[i + 4];
    ushort4 a0, a1;
    a0.x = f2bf(x.x); a0.y = f2bf(x.y); a0.z = f2bf(x.z); a0.w = f2bf(x.w);
    a1.x = f2bf(y.x); a1.y = f2bf(y.y); a1.z = f2bf(y.z); a1.w = f2bf(y.w);
    *(ushort4*)&out[i]     = a0;
    *(ushort4*)&out[i + 4] = a1;
}

// ---------------------------------------------------------------------------
// Transpose + convert: WT[n][k] = bf16(W[k][n]), square N=1024
// ---------------------------------------------------------------------------
__global__ __launch_bounds__(256) void transpose_bf16_kernel(
    const float* __restrict__ W, unsigned short* __restrict__ WT)
{
    __shared__ float t[32][33];
    const int c  = threadIdx.x & 31;
    const int r8 = threadIdx.x >> 5;          // 0..7
    const int k0 = blockIdx.y * 32;
    const int n0 = blockIdx.x * 32;
    #pragma unroll
    for (int i = 0; i < 4; ++i) {
        const int r = r8 + i * 8;
        t[r][c] = W[(size_t)(k0 + r) * 1024 + n0 + c];
    }
    __syncthreads();
    #pragma unroll
    for (int i = 0; i < 4; ++i) {
        const int r = r8 + i * 8;
        WT[(size_t)(n0 + r) * 1024 + k0 + c] = f2bf(t[c][r]);
    }
}

// 3 weight transposes in one launch (z selects)
__global__ __launch_bounds__(256) void trans3_bf16_kernel(
    const float* __restrict__ W0, const float* __restrict__ W1,
    const float* __restrict__ W2,
    unsigned short* __restrict__ T0, unsigned short* __restrict__ T1,
    unsigned short* __restrict__ T2)
{
    __shared__ float t[32][33];
    const float* W = blockIdx.z == 0 ? W0 : blockIdx.z == 1 ? W1 : W2;
    unsigned short* WT = blockIdx.z == 0 ? T0 : blockIdx.z == 1 ? T1 : T2;
    const int c  = threadIdx.x & 31;
    const int r8 = threadIdx.x >> 5;
    const int k0 = blockIdx.y * 32;
    const int n0 = blockIdx.x * 32;
    #pragma unroll
    for (int i = 0; i < 4; ++i) {
        const int r = r8 + i * 8;
        t[r][c] = W[(size_t)(k0 + r) * 1024 + n0 + c];
    }
    __syncthreads();
    #pragma unroll
    for (int i = 0; i < 4; ++i) {
        const int r = r8 + i * 8;
        WT[(size_t)(n0 + r) * 1024 + k0 + c] = f2bf(t[c][r]);
    }
}

// ---------------------------------------------------------------------------
// V transpose (bf16 in): Vb bf16 [B,L,D] -> vtb bf16 [B,H,HD,L]
// ---------------------------------------------------------------------------
__global__ __launch_bounds__(256) void vtrans_bf16_kernel(
    const unsigned short* __restrict__ Vb, unsigned short* __restrict__ vtb)
{
    __shared__ unsigned short t[64][68];
    const int tid = threadIdx.x;
    const int l0  = blockIdx.x * 64;
    const int h   = blockIdx.y;
    const int b   = blockIdx.z;
    const int rr  = tid >> 4;          // 0..15
    const int c4  = (tid & 15) * 4;
    #pragma unroll
    for (int i = 0; i < 4; ++i) {
        const int r = i * 16 + rr;
        *(ushort4*)&t[r][c4] =
            *(const ushort4*)&Vb[((size_t)(b * L_ + l0 + r)) * D_ + h * 64 + c4];
    }
    __syncthreads();
    #pragma unroll
    for (int i = 0; i < 4; ++i) {
        const int d = i * 16 + rr;
        ushort4 o;
        o.x = t[c4 + 0][d]; o.y = t[c4 + 1][d];
        o.z = t[c4 + 2][d]; o.w = t[c4 + 3][d];
        *(ushort4*)&vtb[((size_t)((b * H_ + h) * 64 + d)) * L_ + l0 + c4] = o;
    }
}

// ---------------------------------------------------------------------------
// Pack mask -> per-(query, quad) 16-bit words:
// mbt[((b*32 + kt)*2048 + q)*4 + Q] bit (kr*4+r) = mask key kt*64+kr*16+Q*4+r
// ---------------------------------------------------------------------------
__global__ __launch_bounds__(256) void pack_mask16_kernel(
    const int* __restrict__ mask, unsigned short* __restrict__ mbt)
{
    const unsigned g = blockIdx.x * 256 + threadIdx.x;
    const int v = mask[g];
    const unsigned long long bm = __ballot(v != 0);
    const int lane = threadIdx.x & 63;
    if (lane < 4) {
        const int b  = g >> 22;
        const int q  = (g >> 11) & 2047;
        const int kt = (g >> 6) & 31;
        unsigned long long x = (bm >> (4 * lane)) & 0x000F000F000F000FULL;
        x |= x >> 12;
        x |= x >> 24;
        mbt[((size_t)(b * 32 + kt) * 2048 + q) * 4 + lane] =
            (unsigned short)(x & 0xFFFFu);
    }
}

// ---------------------------------------------------------------------------
// bf16 MFMA GEMM body (m97 recipe), shared by the two GEMM kernels below.
// ---------------------------------------------------------------------------
template<int OUT_BF16>
__device__ static inline void gemm_body(
    const unsigned short* __restrict__ A, const unsigned short* __restrict__ WT,
    const float* __restrict__ bias, void* __restrict__ Cv,
    int M, int N, int K, float omul,
    unsigned short* At, unsigned short* Bt)
{
    const int tid  = threadIdx.x;
    const int lane = tid & 63;
    const int wave = tid >> 6;
    const int wm   = wave >> 1;
    const int wn   = wave & 1;
    const int quad = lane >> 4;
    const int l15  = lane & 15;
    const int m0   = blockIdx.y * 128;
    const int n0   = blockIdx.x * 128;

    f32x4 acc[4][4];
    #pragma unroll
    for (int i = 0; i < 4; ++i)
        #pragma unroll
        for (int j = 0; j < 4; ++j) acc[i][j] = (f32x4)0.f;

    for (int k0 = 0; k0 < K; k0 += 64) {
        __syncthreads();
        #pragma unroll
        for (int i = 0; i < 4; ++i) {
            const int fb  = i * 256 + wave * 64;
            const int f   = fb + lane;
            const int row = f >> 3;
            const int c8  = f & 7;
            async_copy16(&A [(size_t)(m0 + row) * K + k0 + c8 * 8],
                         (char*)At + (size_t)fb * 16);
            async_copy16(&WT[(size_t)(n0 + row) * K + k0 + c8 * 8],
                         (char*)Bt + (size_t)fb * 16);
        }
        __syncthreads();

        #pragma unroll
        for (int kk = 0; kk < 64; kk += 32) {
            short8 afr[4], bfr[4];
            #pragma unroll
            for (int mt = 0; mt < 4; ++mt)
                afr[mt] = *(const short8*)&At[(size_t)(wm * 64 + mt * 16 + l15) * 64 + kk + quad * 8];
            #pragma unroll
            for (int nt = 0; nt < 4; ++nt)
                bfr[nt] = *(const short8*)&Bt[(size_t)(wn * 64 + nt * 16 + l15) * 64 + kk + quad * 8];
            __builtin_amdgcn_s_setprio(1);
            #pragma unroll
            for (int mt = 0; mt < 4; ++mt)
                #pragma unroll
                for (int nt = 0; nt < 4; ++nt)
                    acc[mt][nt] = __builtin_amdgcn_mfma_f32_16x16x32_bf16(
                        afr[mt], bfr[nt], acc[mt][nt], 0, 0, 0);
            __builtin_amdgcn_s_setprio(0);
        }
    }

    #pragma unroll
    for (int nt = 0; nt < 4; ++nt) {
        const int col = n0 + wn * 64 + nt * 16 + l15;
        const float bv = bias[col];
        #pragma unroll
        for (int mt = 0; mt < 4; ++mt) {
            const int r0 = m0 + wm * 64 + mt * 16 + quad * 4;
            #pragma unroll
            for (int r = 0; r < 4; ++r) {
                const float val = (acc[mt][nt][r] + bv) * omul;
                if constexpr (OUT_BF16)
                    ((unsigned short*)Cv)[(size_t)(r0 + r) * N + col] = f2bf(val);
                else
                    ((float*)Cv)[(size_t)(r0 + r) * N + col] = val;
            }
        }
    }
}

// Q/K/V projections in ONE launch (z selects); bf16 out.
__global__ __launch_bounds__(256) void gemm3_mfma_kernel(
    const unsigned short* __restrict__ A0, const unsigned short* __restrict__ A1,
    const unsigned short* __restrict__ A2,
    const unsigned short* __restrict__ W0, const unsigned short* __restrict__ W1,
    const unsigned short* __restrict__ W2,
    const float* __restrict__ b0, const float* __restrict__ b1,
    const float* __restrict__ b2,
    unsigned short* __restrict__ C0, unsigned short* __restrict__ C1,
    unsigned short* __restrict__ C2, float om0)
{
    __shared__ __align__(16) unsigned short At[128 * 64];
    __shared__ __align__(16) unsigned short Bt[128 * 64];
    const int z = blockIdx.z;
    const unsigned short* A  = z == 0 ? A0 : z == 1 ? A1 : A2;
    const unsigned short* WT = z == 0 ? W0 : z == 1 ? W1 : W2;
    const float* bias        = z == 0 ? b0 : z == 1 ? b1 : b2;
    unsigned short* C        = z == 0 ? C0 : z == 1 ? C1 : C2;
    const float omul         = z == 0 ? om0 : 1.f;
    gemm_body<1>(A, WT, bias, C, B_ * L_, D_, D_, omul, At, Bt);
}

// Single GEMM, fp32 out (final projection)
__global__ __launch_bounds__(256) void gemm_mfma_kernel(
    const unsigned short* __restrict__ A, const unsigned short* __restrict__ WT,
    const float* __restrict__ bias, float* __restrict__ C,
    int M, int N, int K)
{
    __shared__ __align__(16) unsigned short At[128 * 64];
    __shared__ __align__(16) unsigned short Bt[128 * 64];
    gemm_body<0>(A, WT, bias, C, M, N, K, 1.f, At, Bt);
}

// ---------------------------------------------------------------------------
// MFMA flash attention, transposed orientation, double-buffered staging.
// - Q pre-scaled by 0.125*log2e (folded into Q-GEMM epilogue).
// - Kt/Vs LDS XOR-swizzled (T2, rule 21): linear LDS dest + inv-swizzled
//   global source chunk + swizzled ds_read.
// - T3-lite: stage tile t+1 BEFORE computing tile t; ONE barrier per tile
//   (its implicit vmcnt drain lands after ~1000cy of compute).
// - T1: XCD-chunked block swizzle so the 16 q-blocks sharing a (b,h) K/V
//   panel land on one XCD (panel set = 8 x 512KB = 4MB = one L2).
// - T5: setprio around MFMA clusters.
// ---------------------------------------------------------------------------
#define AQ 128
#define AK 64
#define PSTR 72   // Pt row stride (bf16): 144B = 16B-aligned, low-conflict
#define NT (L_ / AK)

__global__ __launch_bounds__(256) void attn_mfma_kernel(
    const unsigned short* __restrict__ Qb,
    const unsigned short* __restrict__ Kb,
    const unsigned short* __restrict__ Vtg,
    const unsigned short* __restrict__ mbt,
    unsigned short* __restrict__ Cb)
{
    __shared__ __align__(16) unsigned short Kt[2][AK * 64];   // 2 x 8KB swz
    __shared__ __align__(16) unsigned short Vs[2][64 * AK];   // 2 x 8KB swz
    __shared__ __align__(16) unsigned short Pt[AQ * PSTR];    // 18KB
    __shared__ __align__(16) unsigned short Mt[2][AQ * 4];    // 2 x 1KB

    const int tid  = threadIdx.x;
    const int lane = tid & 63;
    const int w    = tid >> 6;          // wave 0..3: queries w*32..+31
    const int quad = lane >> 4;
    const int l15  = lane & 15;

    // XCD-chunked bijective swizzle (1024 wgs, 8 XCDs, 128/chunk)
    const int nid = (blockIdx.x & 7) * 128 + (blockIdx.x >> 3);
    const int q0  = (nid & 15) * AQ;
    const int h   = (nid >> 4) & 15;
    const int b   = nid >> 8;

    // global base pointers (loop-invariant)
    const unsigned short* kbase = &Kb [((size_t)(b * L_)) * D_ + h * 64];
    const unsigned short* vbase = &Vtg[((size_t)((b * H_ + h) * 64)) * L_];
    const unsigned short* mbase = &mbt[((size_t)(b * 32) * 2048 + q0) * 4];

    // Q fragments (B-operand): [qc][kc], resident in VGPRs (pre-scaled)
    short8 qf[2][2];
    #pragma unroll
    for (int qc = 0; qc < 2; ++qc)
        #pragma unroll
        for (int kc = 0; kc < 2; ++kc)
            qf[qc][kc] = *(const short8*)
                &Qb[((size_t)(b * L_ + q0 + w * 32 + qc * 16 + l15)) * D_
                    + h * 64 + kc * 32 + quad * 8];

    f32x4 ot[4][2];                     // ctx^T acc: [d-tile][q-tile]
    #pragma unroll
    for (int dr = 0; dr < 4; ++dr)
        #pragma unroll
        for (int qc = 0; qc < 2; ++qc) ot[dr][qc] = (f32x4)0.f;
    float m_run[2] = {-INFINITY, -INFINITY};
    float l_run[2] = {0.f, 0.f};

    // staging lambda: issue async global->LDS for tile kt into buffer bi
    auto stage = [&](int bi, int kt) {
        const int k0 = kt * AK;
        #pragma unroll
        for (int i = 0; i < 2; ++i) {
            const int fb = i * 256 + w * 64;
            const int f  = fb + lane;
            const int r  = f >> 3;
            const int cs = (f & 7) ^ (r & 7);
            async_copy16(&kbase[(size_t)(k0 + r) * D_ + cs * 8],
                         (char*)&Kt[bi][0] + fb * 16);
            async_copy16(&vbase[(size_t)r * L_ + k0 + cs * 8],
                         (char*)&Vs[bi][0] + fb * 16);
        }
        if (w == 3)
            async_copy16(&mbase[(size_t)kt * 2048 * 4 + lane * 8],
                         (char*)&Mt[bi][0]);
    };

    stage(0, 0);
    __syncthreads();   // implicit vmcnt(0) drain: tile 0 ready

    for (int kt = 0; kt < NT; ++kt) {
        const int cur = kt & 1;
        if (kt + 1 < NT) stage(cur ^ 1, kt + 1);   // flies under compute

        // ---- S^T = K·Q^T : st[key-tile][q-tile] -------------------------
        f32x4 st[4][2];
        {
            short8 kf[4];
            #pragma unroll
            for (int kr = 0; kr < 4; ++kr)
                kf[kr] = *(const short8*)
                    &Kt[cur][(kr * 16 + l15) * 64 + ((quad ^ (l15 & 7)) * 8)];
            __builtin_amdgcn_s_setprio(1);
            #pragma unroll
            for (int kr = 0; kr < 4; ++kr)
                #pragma unroll
                for (int qc = 0; qc < 2; ++qc)
                    st[kr][qc] = __builtin_amdgcn_mfma_f32_16x16x32_bf16(
                        kf[kr], qf[qc][0], (f32x4)0.f, 0, 0, 0);
            __builtin_amdgcn_s_setprio(0);
        }
        {
            short8 kf[4];
            #pragma unroll
            for (int kr = 0; kr < 4; ++kr)
                kf[kr] = *(const short8*)
                    &Kt[cur][(kr * 16 + l15) * 64 + (((4 + quad) ^ (l15 & 7)) * 8)];
            __builtin_amdgcn_s_setprio(1);
            #pragma unroll
            for (int kr = 0; kr < 4; ++kr)
                #pragma unroll
                for (int qc = 0; qc < 2; ++qc)
                    st[kr][qc] = __builtin_amdgcn_mfma_f32_16x16x32_bf16(
                        kf[kr], qf[qc][1], st[kr][qc], 0, 0, 0);
            __builtin_amdgcn_s_setprio(0);
        }

        // ---- online softmax (per-lane per query) + P write --------------
        #pragma unroll
        for (int qc = 0; qc < 2; ++qc) {
            const unsigned m16 = Mt[cur][(w * 32 + qc * 16 + l15) * 4 + quad];
            float rmax = -INFINITY;
            #pragma unroll
            for (int kr = 0; kr < 4; ++kr) {
                const unsigned nib = (m16 >> (kr * 4)) & 0xFu;
                #pragma unroll
                for (int r = 0; r < 4; ++r) {
                    const float x = ((nib >> r) & 1u) ? st[kr][qc][r] : -INFINITY;
                    st[kr][qc][r] = x;
                    rmax = fmaxf(rmax, x);
                }
            }
            rmax = fmaxf(rmax, __shfl_xor(rmax, 16));
            rmax = fmaxf(rmax, __shfl_xor(rmax, 32));
            // T13 defer-max: skip rescale unless max grew by > 8 (exp2 dom)
            if (__any(rmax > m_run[qc] + 8.f)) {
                const float mnew  = fmaxf(m_run[qc], rmax);
                const float msafe = fmaxf(mnew, -1e30f);
                const float alpha = exp2f(m_run[qc] - msafe);
                l_run[qc] *= alpha;
                #pragma unroll
                for (int dr = 0; dr < 4; ++dr) {
                    ot[dr][qc][0] *= alpha; ot[dr][qc][1] *= alpha;
                    ot[dr][qc][2] *= alpha; ot[dr][qc][3] *= alpha;
                }
                m_run[qc] = mnew;
            }
            const float msafe = fmaxf(m_run[qc], -1e30f);
            float psum = 0.f;
            #pragma unroll
            for (int kr = 0; kr < 4; ++kr) {
                const float p0 = exp2f(st[kr][qc][0] - msafe);
                const float p1 = exp2f(st[kr][qc][1] - msafe);
                const float p2 = exp2f(st[kr][qc][2] - msafe);
                const float p3 = exp2f(st[kr][qc][3] - msafe);
                psum += (p0 + p1) + (p2 + p3);
                uint2 pk;
                pk.x = cvt_pk_bf16(p0, p1);
                pk.y = cvt_pk_bf16(p2, p3);
                *(uint2*)&Pt[(w * 32 + qc * 16 + l15) * PSTR + kr * 16 + quad * 4] = pk;
            }
            psum += __shfl_xor(psum, 16);
            psum += __shfl_xor(psum, 32);
            l_run[qc] += psum;
        }

        // ---- ctx^T += V^T · P^T  (Pt is wave-private; no barrier needed) -
        #pragma unroll
        for (int kc = 0; kc < 2; ++kc) {
            short8 vf[4], pf[2];
            #pragma unroll
            for (int dr = 0; dr < 4; ++dr)
                vf[dr] = *(const short8*)
                    &Vs[cur][(dr * 16 + l15) * 64 + (((kc * 4 + quad) ^ (l15 & 7)) * 8)];
            #pragma unroll
            for (int qc = 0; qc < 2; ++qc)
                pf[qc] = *(const short8*)&Pt[(w * 32 + qc * 16 + l15) * PSTR
                                             + kc * 32 + quad * 8];
            __builtin_amdgcn_s_setprio(1);
            #pragma unroll
            for (int dr = 0; dr < 4; ++dr)
                #pragma unroll
                for (int qc = 0; qc < 2; ++qc)
                    ot[dr][qc] = __builtin_amdgcn_mfma_f32_16x16x32_bf16(
                        vf[dr], pf[qc], ot[dr][qc], 0, 0, 0);
            __builtin_amdgcn_s_setprio(0);
        }

        // one barrier/tile: drains next tile's loads (mostly complete) and
        // publishes "all waves done reading buffer cur"
        __syncthreads();
    }

    // ---- epilogue: normalize, store ctx as bf16 [B,L,D] -----------------
    #pragma unroll
    for (int qc = 0; qc < 2; ++qc) {
        const float rinv = (l_run[qc] > 0.f) ? (1.f / l_run[qc]) : 0.f;
        const size_t base = ((size_t)(b * L_ + q0 + w * 32 + qc * 16 + l15)) * D_
                            + h * 64;
        #pragma unroll
        for (int dr = 0; dr < 4; ++dr) {
            ushort4 o;
            o.x = f2bf(ot[dr][qc][0] * rinv);
            o.y = f2bf(ot[dr][qc][1] * rinv);
            o.z = f2bf(ot[dr][qc][2] * rinv);
            o.w = f2bf(ot[dr][qc][3] * rinv);
            *(ushort4*)&Cb[base + dr * 16 + quad * 4] = o;
        }
    }
}

// ---------------------------------------------------------------------------
extern "C" void kernel_launch(void* const* d_in, const int* in_sizes, int n_in,
                              void* d_out, int out_size, void* d_ws, size_t ws_size,
                              hipStream_t stream)
{
    const float* q    = (const float*)d_in[0];
    const float* k    = (const float*)d_in[1];
    const float* v    = (const float*)d_in[2];
    const int*   mask = (const int*)d_in[3];
    const float* WQ   = (const float*)d_in[4];
    const float* bQ   = (const float*)d_in[5];
    const float* WK   = (const float*)d_in[6];
    const float* bK   = (const float*)d_in[7];
    const float* WV   = (const float*)d_in[8];
    const float* bV   = (const float*)d_in[9];
    const float* WO   = (const float*)d_in[10];
    const float* bO   = (const float*)d_in[11];
    float* out = (float*)d_out;

    const size_t NTOK = (size_t)B_ * L_;        // 8192

    // ws map (128 MiB): 8 x 16MB bf16 zones
    char* W = (char*)d_ws;
    unsigned short* qin = (unsigned short*)(W);                        // 16MB
    unsigned short* kin = (unsigned short*)(W + ((size_t)16  << 20));  // 16MB
    unsigned short* vin = (unsigned short*)(W + ((size_t)32  << 20));  // 16MB
    unsigned short* qbf = (unsigned short*)(W + ((size_t)48  << 20));  // 16MB
    unsigned short* kbf = (unsigned short*)(W + ((size_t)64  << 20));  // 16MB
    unsigned short* vbf = (unsigned short*)(W + ((size_t)80  << 20));  // 16MB
    unsigned short* vtb = (unsigned short*)(W + ((size_t)96  << 20));  // 16MB
    unsigned short* cb  = (unsigned short*)(W + ((size_t)112 << 20));  // 16MB
    // WTo reuses vin zone (dead after the fused QKV GEMM); must live in ws,
    // NOT d_out, because the final GEMM writes out over all of d_out.
    unsigned short* WTo = vin;

    // d_out as scratch until final GEMM (all dead before the out-write):
    unsigned short* mbt16 = (unsigned short*)d_out;                          // 2MB
    unsigned short* WTq = (unsigned short*)((char*)d_out + ((size_t)2 << 20));
    unsigned short* WTk = (unsigned short*)((char*)d_out + ((size_t)4 << 20));
    unsigned short* WTv = (unsigned short*)((char*)d_out + ((size_t)6 << 20));

    pack_mask16_kernel<<<(B_ * L_ * L_) / 256, 256, 0, stream>>>(mask, mbt16);

    const int cvtg = (int)(NTOK * D_ / (256 * 8));   // 4096
    cvt3_bf16_kernel<<<dim3(cvtg, 3), 256, 0, stream>>>(q, k, v, qin, kin, vin);

    trans3_bf16_kernel<<<dim3(32, 32, 3), 256, 0, stream>>>(
        WQ, WK, WV, WTq, WTk, WTv);

    // Projections, bf16 out, one launch. Q gets scale*log2e folded in.
    const float qscale = 0.125f * 1.44269504088896340736f;
    dim3 ggrd3(D_ / 128, NTOK / 128, 3);        // (8, 64, 3) = 1536 wgs
    gemm3_mfma_kernel<<<ggrd3, 256, 0, stream>>>(
        qin, kin, vin, WTq, WTk, WTv, bQ, bK, bV, qbf, kbf, vbf, qscale);

    // WO transpose into vin zone (dead now); V transpose to [B,H,HD,L]
    transpose_bf16_kernel<<<dim3(32, 32), 256, 0, stream>>>(WO, WTo);
    vtrans_bf16_kernel<<<dim3(L_ / 64, H_, B_), 256, 0, stream>>>(vbf, vtb);

    attn_mfma_kernel<<<dim3(1024), 256, 0, stream>>>(qbf, kbf, vtb, mbt16, cb);

    dim3 ggrd(D_ / 128, NTOK / 128);            // (8, 64)
    gemm_mfma_kernel<<<ggrd, 256, 0, stream>>>(cb, WTo, bO, out, (int)NTOK, D_, D_);
}